// Round 1
// baseline (582.515 us; speedup 1.0000x reference)
//
#include <hip/hip_runtime.h>
#include <hip/hip_bf16.h>
#include <hip/hip_fp16.h>

// Problem: B=16, N=512, D=512, H=8, DH=64, PD=9, HID=32
// ws layout (floats):
//   q        [16][8][512][64]  @ 0         (4,194,304 f)
//   k        same              @ 4194304
//   v        same              @ 8388608
//   attn_out [16][512][512]    @ 12582912
//   bias fp16 [16][8][512][512] @ byte 67108864  (67 MB)
// total ws required: 128 MiB

#define BB 16
#define NN 512
#define DD 512
#define HH 8
#define DHH 64

// ---------------- QKV projection GEMM: [8192,512] @ [512,1536] ----------------
__global__ __launch_bounds__(256) void qkv_gemm(
    const float* __restrict__ hmat, const float* __restrict__ W,
    float* __restrict__ q, float* __restrict__ k, float* __restrict__ v) {
  __shared__ __align__(16) float As[16][68];  // [BK][BM+pad4] transposed
  __shared__ __align__(16) float Bs[16][64];  // [BK][BN]
  const int tid = threadIdx.x;
  const int row0 = blockIdx.x * 64;
  const int col0 = blockIdx.y * 64;
  const int tr = tid >> 4, tc = tid & 15;
  float acc[4][4] = {};
  for (int k0 = 0; k0 < DD; k0 += 16) {
    {
      const int r = tid >> 2;
      const int c4 = (tid & 3) << 2;
      float4 a = *(const float4*)&hmat[(row0 + r) * DD + k0 + c4];
      As[c4 + 0][r] = a.x; As[c4 + 1][r] = a.y;
      As[c4 + 2][r] = a.z; As[c4 + 3][r] = a.w;
    }
    {
      const int r = tid >> 4;
      const int c4 = (tid & 15) << 2;
      *(float4*)&Bs[r][c4] = *(const float4*)&W[(k0 + r) * (3 * DD) + col0 + c4];
    }
    __syncthreads();
#pragma unroll
    for (int kk = 0; kk < 16; ++kk) {
      const float4 a = *(const float4*)&As[kk][tr << 2];
      const float4 b = *(const float4*)&Bs[kk][tc << 2];
      const float av[4] = {a.x, a.y, a.z, a.w};
      const float bv[4] = {b.x, b.y, b.z, b.w};
#pragma unroll
      for (int i = 0; i < 4; ++i)
#pragma unroll
        for (int j = 0; j < 4; ++j) acc[i][j] = fmaf(av[i], bv[j], acc[i][j]);
    }
    __syncthreads();
  }
  // scatter: this 64-col tile lies entirely in one (part, head)
  const int part = col0 >> 9;          // 0=q 1=k 2=v
  const int head = (col0 & 511) >> 6;  // 64-wide head slice
  float* dst = (part == 0) ? q : ((part == 1) ? k : v);
#pragma unroll
  for (int i = 0; i < 4; ++i) {
    const int row = row0 + tr * 4 + i;
    const int b_ = row >> 9, n_ = row & 511;
    float4 val = make_float4(acc[i][0], acc[i][1], acc[i][2], acc[i][3]);
    *(float4*)&dst[(((b_ * HH + head) * NN) + n_) * DHH + (tc << 2)] = val;
  }
}

// ---------------- pairwise bias MLP -> fp16 bias[b][h][i][j] ----------------
__global__ __launch_bounds__(256) void bias_mlp(
    const float* __restrict__ v, const int* __restrict__ tti,
    const float* __restrict__ W1, const float* __restrict__ b1,
    const float* __restrict__ W2, const float* __restrict__ b2,
    __half* __restrict__ bias) {
  __shared__ float sW1[9][32];
  __shared__ float sW2[32][8];
  __shared__ float sb1[32];
  __shared__ float sb2[8];
  __shared__ int sTT[NN];
  const int tid = threadIdx.x;
  const int i = blockIdx.x;
  const int b = blockIdx.y;
  for (int idx = tid; idx < 9 * 32; idx += 256) sW1[idx / 32][idx % 32] = W1[idx];
  if (tid < 32 * 8) sW2[tid >> 3][tid & 7] = W2[tid];
  if (tid < 32) sb1[tid] = b1[tid];
  if (tid < 8) sb2[tid] = b2[tid];
  for (int idx = tid; idx < NN; idx += 256) sTT[idx] = tti[idx];
  __syncthreads();
  const float4 vi = *(const float4*)&v[(b * NN + i) * 4];
  const int ti = sTT[i];
  const int j0 = tid * 2;  // 2 adjacent j per thread
  float hout[2][8];
#pragma unroll
  for (int jj = 0; jj < 2; ++jj) {
    const int j = j0 + jj;
    const float4 vj = *(const float4*)&v[(b * NN + j) * 4];
    const float same = (ti == sTT[j]) ? 1.f : 0.f;
    const float a0 = vi.x - vj.x, a1 = vi.y - vj.y, a2 = vi.z - vj.z, a3 = vi.w - vj.w;
    const float p0 = vi.x * vj.x, p1 = vi.y * vj.y, p2 = vi.z * vj.z, p3 = vi.w * vj.w;
    float hacc[8];
#pragma unroll
    for (int hh = 0; hh < 8; ++hh) hacc[hh] = sb2[hh];
    for (int c = 0; c < 32; ++c) {
      float x = fmaf(same, sW1[8][c], sb1[c]);
      x = fmaf(a0, sW1[0][c], x); x = fmaf(a1, sW1[1][c], x);
      x = fmaf(a2, sW1[2][c], x); x = fmaf(a3, sW1[3][c], x);
      x = fmaf(p0, sW1[4][c], x); x = fmaf(p1, sW1[5][c], x);
      x = fmaf(p2, sW1[6][c], x); x = fmaf(p3, sW1[7][c], x);
      x = fmaxf(x, 0.f);
#pragma unroll
      for (int hh = 0; hh < 8; ++hh) hacc[hh] = fmaf(x, sW2[c][hh], hacc[hh]);
    }
#pragma unroll
    for (int hh = 0; hh < 8; ++hh) hout[jj][hh] = hacc[hh];
  }
#pragma unroll
  for (int hh = 0; hh < 8; ++hh) {
    __half2 pr;
    pr.x = __float2half(hout[0][hh]);
    pr.y = __float2half(hout[1][hh]);
    *(__half2*)&bias[(((size_t)(b * HH + hh) * NN) + i) * NN + j0] = pr;
  }
}

// ---------------- fused flash attention with precomputed bias ----------------
// block = (i-tile of 32, head, batch); 256 threads
__global__ __launch_bounds__(256) void attn_fused(
    const float* __restrict__ q, const float* __restrict__ k, const float* __restrict__ v,
    const __half* __restrict__ bias, const int* __restrict__ msk,
    float* __restrict__ out) {
  __shared__ __align__(16) float qs[32][64];
  __shared__ __align__(16) float vs[64][68];  // pad breaks stride-64 conflicts
  __shared__ float S[32][65];
  __shared__ float row_max[32], row_sum[32], row_alpha[32];
  const int tid = threadIdx.x;
  const int it = blockIdx.x;
  const int h_ = blockIdx.y;
  const int b_ = blockIdx.z;
  const float* qbase = q + (((b_ * HH + h_) * NN) + it * 32) * DHH;
  const float* kbase = k + ((b_ * HH + h_) * NN) * DHH;
  const float* vbase = v + ((b_ * HH + h_) * NN) * DHH;
  const __half* bbase = bias + (((size_t)(b_ * HH + h_) * NN) + it * 32) * NN;
  const int* mbase = msk + b_ * NN;
  for (int idx = tid; idx < 32 * 16; idx += 256) {
    const int r = idx >> 4, c4 = (idx & 15) << 2;
    *(float4*)&qs[r][c4] = *(const float4*)&qbase[r * DHH + c4];
  }
  if (tid < 32) { row_max[tid] = -1e30f; row_sum[tid] = 0.f; }
  const int i_l = tid >> 3;          // output row owned by this thread
  const int dh0 = (tid & 7) << 3;    // 8 consecutive dh
  float acc[8] = {};
  for (int j0 = 0; j0 < NN; j0 += 64) {
    __syncthreads();  // prev PV done; qs/stats visible on first iter
    // stage V tile (coalesced)
    for (int idx = tid; idx < 64 * 16; idx += 256) {
      const int r = idx >> 4, c4 = (idx & 15) << 2;
      *(float4*)&vs[r][c4] = *(const float4*)&vbase[(j0 + r) * DHH + c4];
    }
    // S[i][jj] = q·k/8 + bias, masked
    {
      const int jj = tid & 63;
      const int ib = (tid >> 6) << 3;  // wave-uniform
      const float* krow = kbase + (j0 + jj) * DHH;
      float4 kr[16];
#pragma unroll
      for (int t = 0; t < 16; ++t) kr[t] = *(const float4*)&krow[t << 2];
      const bool valid = (mbase[j0 + jj] != 0);
#pragma unroll
      for (int ii = 0; ii < 8; ++ii) {
        const int i = ib + ii;
        float s = 0.f;
#pragma unroll
        for (int t = 0; t < 16; ++t) {
          const float4 q4 = *(const float4*)&qs[i][t << 2];  // wave-broadcast
          s = fmaf(q4.x, kr[t].x, s);
          s = fmaf(q4.y, kr[t].y, s);
          s = fmaf(q4.z, kr[t].z, s);
          s = fmaf(q4.w, kr[t].w, s);
        }
        const float bb = __half2float(bbase[(size_t)i * NN + j0 + jj]);
        S[i][jj] = valid ? fmaf(s, 0.125f, bb) : -1e30f;
      }
    }
    __syncthreads();
    // online softmax update for this tile (8 lanes per row)
    {
      const int row = tid >> 3;
      const int sub = tid & 7;
      float tmax = -1e30f;
#pragma unroll
      for (int t = 0; t < 8; ++t) tmax = fmaxf(tmax, S[row][sub * 8 + t]);
      tmax = fmaxf(tmax, __shfl_xor(tmax, 1));
      tmax = fmaxf(tmax, __shfl_xor(tmax, 2));
      tmax = fmaxf(tmax, __shfl_xor(tmax, 4));
      const float m_old = row_max[row];
      const float m_new = fmaxf(m_old, tmax);
      float tsum = 0.f;
#pragma unroll
      for (int t = 0; t < 8; ++t) {
        const float p = __expf(S[row][sub * 8 + t] - m_new);
        S[row][sub * 8 + t] = p;
        tsum += p;
      }
      tsum += __shfl_xor(tsum, 1);
      tsum += __shfl_xor(tsum, 2);
      tsum += __shfl_xor(tsum, 4);
      if (sub == 0) {
        const float alpha = __expf(m_old - m_new);
        row_alpha[row] = alpha;
        row_sum[row] = fmaf(row_sum[row], alpha, tsum);
        row_max[row] = m_new;
      }
    }
    __syncthreads();
    // PV accumulate
    {
      const float alpha = row_alpha[i_l];
#pragma unroll
      for (int d = 0; d < 8; ++d) acc[d] *= alpha;
      for (int jj = 0; jj < 64; ++jj) {
        const float p = S[i_l][jj];  // 8-lane broadcast
        const float4 v0 = *(const float4*)&vs[jj][dh0];
        const float4 v1 = *(const float4*)&vs[jj][dh0 + 4];
        acc[0] = fmaf(p, v0.x, acc[0]); acc[1] = fmaf(p, v0.y, acc[1]);
        acc[2] = fmaf(p, v0.z, acc[2]); acc[3] = fmaf(p, v0.w, acc[3]);
        acc[4] = fmaf(p, v1.x, acc[4]); acc[5] = fmaf(p, v1.y, acc[5]);
        acc[6] = fmaf(p, v1.z, acc[6]); acc[7] = fmaf(p, v1.w, acc[7]);
      }
    }
  }
  const float inv = 1.0f / row_sum[i_l];
  float* obase = out + (size_t)(b_ * NN + it * 32 + i_l) * DD + h_ * DHH + dh0;
  float4 o0 = make_float4(acc[0] * inv, acc[1] * inv, acc[2] * inv, acc[3] * inv);
  float4 o1 = make_float4(acc[4] * inv, acc[5] * inv, acc[6] * inv, acc[7] * inv);
  *(float4*)&obase[0] = o0;
  *(float4*)&obase[4] = o1;
}

// ---------------- output GEMM + row mask: [8192,512] @ [512,512] ----------------
__global__ __launch_bounds__(256) void out_gemm(
    const float* __restrict__ A, const float* __restrict__ W,
    const int* __restrict__ msk, float* __restrict__ out) {
  __shared__ __align__(16) float As[16][68];
  __shared__ __align__(16) float Bs[16][64];
  const int tid = threadIdx.x;
  const int row0 = blockIdx.x * 64;
  const int col0 = blockIdx.y * 64;
  const int tr = tid >> 4, tc = tid & 15;
  float acc[4][4] = {};
  for (int k0 = 0; k0 < DD; k0 += 16) {
    {
      const int r = tid >> 2;
      const int c4 = (tid & 3) << 2;
      float4 a = *(const float4*)&A[(row0 + r) * DD + k0 + c4];
      As[c4 + 0][r] = a.x; As[c4 + 1][r] = a.y;
      As[c4 + 2][r] = a.z; As[c4 + 3][r] = a.w;
    }
    {
      const int r = tid >> 4;
      const int c4 = (tid & 15) << 2;
      *(float4*)&Bs[r][c4] = *(const float4*)&W[(k0 + r) * DD + col0 + c4];
    }
    __syncthreads();
#pragma unroll
    for (int kk = 0; kk < 16; ++kk) {
      const float4 a = *(const float4*)&As[kk][tr << 2];
      const float4 b = *(const float4*)&Bs[kk][tc << 2];
      const float av[4] = {a.x, a.y, a.z, a.w};
      const float bv[4] = {b.x, b.y, b.z, b.w};
#pragma unroll
      for (int i = 0; i < 4; ++i)
#pragma unroll
        for (int j = 0; j < 4; ++j) acc[i][j] = fmaf(av[i], bv[j], acc[i][j]);
    }
    __syncthreads();
  }
#pragma unroll
  for (int i = 0; i < 4; ++i) {
    const int row = row0 + tr * 4 + i;
    const float mm = (msk[row] != 0) ? 1.f : 0.f;
    float4 val = make_float4(acc[i][0] * mm, acc[i][1] * mm, acc[i][2] * mm, acc[i][3] * mm);
    *(float4*)&out[(size_t)row * DD + col0 + (tc << 2)] = val;
  }
}

extern "C" void kernel_launch(void* const* d_in, const int* in_sizes, int n_in,
                              void* d_out, int out_size, void* d_ws, size_t ws_size,
                              hipStream_t stream) {
  const float* h     = (const float*)d_in[0];
  const float* v     = (const float*)d_in[1];
  const int*   m     = (const int*)d_in[2];
  const int*   tti   = (const int*)d_in[3];
  const float* W_qkv = (const float*)d_in[4];
  const float* W_out = (const float*)d_in[5];
  const float* W1    = (const float*)d_in[6];
  const float* b1    = (const float*)d_in[7];
  const float* W2    = (const float*)d_in[8];
  const float* b2    = (const float*)d_in[9];
  float* out = (float*)d_out;
  float* ws = (float*)d_ws;

  float* q        = ws;
  float* k        = ws + 4194304;
  float* vv       = ws + 8388608;
  float* attn_out = ws + 12582912;
  __half* bias    = (__half*)(ws + 16777216);

  qkv_gemm<<<dim3(128, 24), 256, 0, stream>>>(h, W_qkv, q, k, vv);
  bias_mlp<<<dim3(512, 16), 256, 0, stream>>>(v, tti, W1, b1, W2, b2, bias);
  attn_fused<<<dim3(16, 8, 16), 256, 0, stream>>>(q, k, vv, bias, m, attn_out);
  out_gemm<<<dim3(128, 8), 256, 0, stream>>>(attn_out, W_out, m, out);
}

// Round 2
// 213.072 us; speedup vs baseline: 2.7339x; 2.7339x over previous
//
#include <hip/hip_runtime.h>
#include <hip/hip_bf16.h>
#include <hip/hip_fp16.h>

// B=16, N=512, D=512, H=8, DH=64, PD=9, HID=32
#define NN 512
#define HH 8
#define DHH 64

typedef __attribute__((ext_vector_type(8))) short short8v;
typedef __attribute__((ext_vector_type(8))) unsigned short ushort8v;
typedef __attribute__((ext_vector_type(4))) unsigned short ushort4v;
typedef __attribute__((ext_vector_type(4))) float f32x4;

__device__ __forceinline__ unsigned short f2bf(float x) {
  unsigned u = __builtin_bit_cast(unsigned, x);
  u += 0x7FFFu + ((u >> 16) & 1u);
  return (unsigned short)(u >> 16);
}
// swizzles: XOR a row-dependent 16B slot into the byte-column (T2, rule #21 both-sides)
__device__ __forceinline__ int swz64(int r, int cb) { return r * 64 + (cb ^ (((r >> 1) & 3) << 4)); }
__device__ __forceinline__ int swz128(int r, int cb) { return r * 128 + (cb ^ ((r & 7) << 4)); }

// ---------------- fp32 -> bf16 elementwise ----------------
__global__ __launch_bounds__(256) void cvt_bf(const float* __restrict__ src,
                                              unsigned short* __restrict__ dst, int n) {
  int i = (blockIdx.x * 256 + threadIdx.x) * 4;
  if (i < n) {
    float4 v = *(const float4*)&src[i];
    ushort4v o;
    o[0] = f2bf(v.x); o[1] = f2bf(v.y); o[2] = f2bf(v.z); o[3] = f2bf(v.w);
    *(ushort4v*)&dst[i] = o;
  }
}

// ---------------- transpose + cvt: src fp32 [R][C] -> dst bf16 [C][R] ----------------
__global__ __launch_bounds__(256) void transpose_cvt(const float* __restrict__ src,
                                                     unsigned short* __restrict__ dst,
                                                     int R, int C) {
  __shared__ float t[32][33];
  const int r0 = blockIdx.x * 32, c0 = blockIdx.y * 32;
  const int rr = threadIdx.x >> 3, c4 = (threadIdx.x & 7) * 4;
  float4 v = *(const float4*)&src[(size_t)(r0 + rr) * C + c0 + c4];
  t[rr][c4 + 0] = v.x; t[rr][c4 + 1] = v.y; t[rr][c4 + 2] = v.z; t[rr][c4 + 3] = v.w;
  __syncthreads();
  ushort4v o;
#pragma unroll
  for (int e = 0; e < 4; ++e) o[e] = f2bf(t[c4 + e][rr]);
  *(ushort4v*)&dst[(size_t)(c0 + rr) * R + r0 + c4] = o;
}

// ---------------- shared 128x128 bf16 MFMA GEMM body (BK=32, 4 waves) ----------------
__device__ __forceinline__ void gemm128_body(const unsigned short* __restrict__ A,
                                             const unsigned short* __restrict__ Bt,
                                             int ldk, int m0, int n0,
                                             f32x4 acc[4][4], unsigned char* smem) {
  const int tid = threadIdx.x, lane = tid & 63, wid = tid >> 6;
  const int wm = wid >> 1, wn = wid & 1;
  int aoff[4], boff[4];
#pragma unroll
  for (int i = 0; i < 4; ++i) {
    aoff[i] = swz64(wm * 64 + i * 16 + (lane & 15), (lane >> 4) * 16);
    boff[i] = 8192 + swz64(wn * 64 + i * 16 + (lane & 15), (lane >> 4) * 16);
  }
  for (int k0 = 0; k0 < ldk; k0 += 32) {
#pragma unroll
    for (int p = 0; p < 2; ++p) {
      const int idx = p * 256 + tid;
      const int r = idx >> 2, cg = idx & 3;
      ushort8v av = *(const ushort8v*)&A[(size_t)(m0 + r) * ldk + k0 + cg * 8];
      *(ushort8v*)&smem[swz64(r, cg * 16)] = av;
      ushort8v bv = *(const ushort8v*)&Bt[(size_t)(n0 + r) * ldk + k0 + cg * 8];
      *(ushort8v*)&smem[8192 + swz64(r, cg * 16)] = bv;
    }
    __syncthreads();
    short8v a[4], b[4];
#pragma unroll
    for (int i = 0; i < 4; ++i) {
      a[i] = *(const short8v*)&smem[aoff[i]];
      b[i] = *(const short8v*)&smem[boff[i]];
    }
#pragma unroll
    for (int i = 0; i < 4; ++i)
#pragma unroll
      for (int j = 0; j < 4; ++j)
        acc[i][j] = __builtin_amdgcn_mfma_f32_16x16x32_bf16(a[i], b[j], acc[i][j], 0, 0, 0);
    __syncthreads();
  }
}

// ---------------- QKV GEMM: h_bf[8192][512] @ WqT[1536][512]^T -> q/k/v bf16 ----------------
__global__ __launch_bounds__(256) void gemm_qkv(const unsigned short* __restrict__ A,
                                                const unsigned short* __restrict__ Bt,
                                                unsigned short* __restrict__ q,
                                                unsigned short* __restrict__ k,
                                                unsigned short* __restrict__ v) {
  __shared__ unsigned char smem[16384];
  f32x4 acc[4][4];
  const f32x4 z = {0.f, 0.f, 0.f, 0.f};
#pragma unroll
  for (int i = 0; i < 4; ++i)
#pragma unroll
    for (int j = 0; j < 4; ++j) acc[i][j] = z;
  gemm128_body(A, Bt, 512, blockIdx.x * 128, blockIdx.y * 128, acc, smem);
  const int lane = threadIdx.x & 63, wid = threadIdx.x >> 6;
  const int wm = wid >> 1, wn = wid & 1;
#pragma unroll
  for (int i = 0; i < 4; ++i) {
    const int row0 = blockIdx.x * 128 + wm * 64 + i * 16 + ((lane >> 4) << 2);
#pragma unroll
    for (int j = 0; j < 4; ++j) {
      const int col = blockIdx.y * 128 + wn * 64 + j * 16 + (lane & 15);
      const int part = col >> 9, head = (col >> 6) & 7, dh = col & 63;
      unsigned short* dst = (part == 0) ? q : ((part == 1) ? k : v);
#pragma unroll
      for (int rr = 0; rr < 4; ++rr) {
        const int row = row0 + rr;
        const int b_ = row >> 9, n_ = row & 511;
        dst[(((b_ * HH + head) * NN) + n_) * DHH + dh] = f2bf(acc[i][j][rr]);
      }
    }
  }
}

// ---------------- out GEMM: ao_bf[8192][512] @ WoT[512][512]^T -> fp32 out (masked) ----------------
__global__ __launch_bounds__(256) void gemm_out(const unsigned short* __restrict__ A,
                                                const unsigned short* __restrict__ Bt,
                                                const int* __restrict__ msk,
                                                float* __restrict__ out) {
  __shared__ unsigned char smem[16384];
  f32x4 acc[4][4];
  const f32x4 z = {0.f, 0.f, 0.f, 0.f};
#pragma unroll
  for (int i = 0; i < 4; ++i)
#pragma unroll
    for (int j = 0; j < 4; ++j) acc[i][j] = z;
  gemm128_body(A, Bt, 512, blockIdx.x * 128, blockIdx.y * 128, acc, smem);
  const int lane = threadIdx.x & 63, wid = threadIdx.x >> 6;
  const int wm = wid >> 1, wn = wid & 1;
#pragma unroll
  for (int i = 0; i < 4; ++i) {
    const int row0 = blockIdx.x * 128 + wm * 64 + i * 16 + ((lane >> 4) << 2);
#pragma unroll
    for (int j = 0; j < 4; ++j) {
      const int col = blockIdx.y * 128 + wn * 64 + j * 16 + (lane & 15);
#pragma unroll
      for (int rr = 0; rr < 4; ++rr) {
        const int row = row0 + rr;
        const float mm = (msk[row] != 0) ? 1.f : 0.f;
        out[(size_t)row * 512 + col] = acc[i][j][rr] * mm;
      }
    }
  }
}

// ---------------- pairwise bias MLP -> fp16 bias[b][h][i][j] ----------------
__global__ __launch_bounds__(256) void bias_mlp(
    const float* __restrict__ v, const int* __restrict__ tti,
    const float* __restrict__ W1, const float* __restrict__ b1,
    const float* __restrict__ W2, const float* __restrict__ b2,
    __half* __restrict__ bias) {
  __shared__ float sW1[9][32];
  __shared__ float sW2[32][8];
  __shared__ float sb1[32];
  __shared__ float sb2[8];
  __shared__ int sTT[NN];
  const int tid = threadIdx.x;
  const int i = blockIdx.x;
  const int b = blockIdx.y;
  for (int idx = tid; idx < 9 * 32; idx += 256) sW1[idx / 32][idx % 32] = W1[idx];
  if (tid < 32 * 8) sW2[tid >> 3][tid & 7] = W2[tid];
  if (tid < 32) sb1[tid] = b1[tid];
  if (tid < 8) sb2[tid] = b2[tid];
  for (int idx = tid; idx < NN; idx += 256) sTT[idx] = tti[idx];
  __syncthreads();
  const float4 vi = *(const float4*)&v[(b * NN + i) * 4];
  const int ti = sTT[i];
  const int j0 = tid * 2;
  float hout[2][8];
#pragma unroll
  for (int jj = 0; jj < 2; ++jj) {
    const int j = j0 + jj;
    const float4 vj = *(const float4*)&v[(b * NN + j) * 4];
    const float same = (ti == sTT[j]) ? 1.f : 0.f;
    const float a0 = vi.x - vj.x, a1 = vi.y - vj.y, a2 = vi.z - vj.z, a3 = vi.w - vj.w;
    const float p0 = vi.x * vj.x, p1 = vi.y * vj.y, p2 = vi.z * vj.z, p3 = vi.w * vj.w;
    float hacc[8];
#pragma unroll
    for (int hh = 0; hh < 8; ++hh) hacc[hh] = sb2[hh];
    for (int c = 0; c < 32; ++c) {
      float x = fmaf(same, sW1[8][c], sb1[c]);
      x = fmaf(a0, sW1[0][c], x); x = fmaf(a1, sW1[1][c], x);
      x = fmaf(a2, sW1[2][c], x); x = fmaf(a3, sW1[3][c], x);
      x = fmaf(p0, sW1[4][c], x); x = fmaf(p1, sW1[5][c], x);
      x = fmaf(p2, sW1[6][c], x); x = fmaf(p3, sW1[7][c], x);
      x = fmaxf(x, 0.f);
#pragma unroll
      for (int hh = 0; hh < 8; ++hh) hacc[hh] = fmaf(x, sW2[c][hh], hacc[hh]);
    }
#pragma unroll
    for (int hh = 0; hh < 8; ++hh) hout[jj][hh] = hacc[hh];
  }
#pragma unroll
  for (int hh = 0; hh < 8; ++hh) {
    __half2 pr;
    pr.x = __float2half(hout[0][hh]);
    pr.y = __float2half(hout[1][hh]);
    *(__half2*)&bias[(((size_t)(b * HH + hh) * NN) + i) * NN + j0] = pr;
  }
}

// ---------------- MFMA flash attention ----------------
// block = (it: 64 q-rows, h, b); 4 waves, wave w owns rows it*64 + w*16 .. +15
__global__ __launch_bounds__(256) void attn_mfma(
    const unsigned short* __restrict__ q, const unsigned short* __restrict__ k,
    const unsigned short* __restrict__ v, const __half* __restrict__ bias,
    const int* __restrict__ msk, unsigned short* __restrict__ ao) {
  __shared__ unsigned char vt[8192];     // V^T tile, [64 dh][128B row] swizzled
  __shared__ unsigned char ps[4][2048];  // per-wave P tile [16][128B] swizzled
  __shared__ float smask[NN];
  const int tid = threadIdx.x, lane = tid & 63, w = tid >> 6;
  const int it = blockIdx.x, h_ = blockIdx.y, b_ = blockIdx.z;
  const int bh = b_ * HH + h_;
  const unsigned short* qb = q + ((size_t)bh * NN + it * 64) * DHH;
  const unsigned short* kb = k + (size_t)bh * NN * DHH;
  const unsigned short* vb = v + (size_t)bh * NN * DHH;
  const __half* bb = bias + (size_t)bh * NN * NN;
  for (int j = tid; j < NN; j += 256) smask[j] = (msk[b_ * NN + j] != 0) ? 0.f : -1e30f;
  // Q fragments (row = lane&15 within wave's 16 rows; k-slice = (lane>>4)*8)
  short8v qf[2];
#pragma unroll
  for (int kc = 0; kc < 2; ++kc)
    qf[kc] = *(const short8v*)&qb[(w * 16 + (lane & 15)) * DHH + kc * 32 + (lane >> 4) * 8];
  f32x4 acc[4];
  const f32x4 z = {0.f, 0.f, 0.f, 0.f};
#pragma unroll
  for (int d = 0; d < 4; ++d) acc[d] = z;
  float mrow[4], lrow[4];
#pragma unroll
  for (int r = 0; r < 4; ++r) { mrow[r] = -1e30f; lrow[r] = 0.f; }
  __syncthreads();
  const int irow_base = it * 64 + w * 16 + ((lane >> 4) << 2);
  for (int j0 = 0; j0 < NN; j0 += 64) {
    // stage V^T (all threads, swizzled scalar writes)
#pragma unroll
    for (int p = 0; p < 2; ++p) {
      const int idx = p * 256 + tid;
      const int j = idx & 63, dh0 = (idx >> 6) * 8;
      ushort8v v8 = *(const ushort8v*)&vb[(j0 + j) * DHH + dh0];
#pragma unroll
      for (int e = 0; e < 8; ++e)
        *(unsigned short*)&vt[swz128(dh0 + e, 2 * j)] = v8[e];
    }
    // S = Q K^T (K fragments straight from global/L2)
    f32x4 s[4];
#pragma unroll
    for (int jt = 0; jt < 4; ++jt) {
      const unsigned short* kr = &kb[(j0 + jt * 16 + (lane & 15)) * DHH + (lane >> 4) * 8];
      short8v kf0 = *(const short8v*)&kr[0];
      short8v kf1 = *(const short8v*)&kr[32];
      f32x4 t = z;
      t = __builtin_amdgcn_mfma_f32_16x16x32_bf16(qf[0], kf0, t, 0, 0, 0);
      t = __builtin_amdgcn_mfma_f32_16x16x32_bf16(qf[1], kf1, t, 0, 0, 0);
      s[jt] = t;
    }
    // scale + bias + mask
#pragma unroll
    for (int jt = 0; jt < 4; ++jt) {
      const int jcol = j0 + jt * 16 + (lane & 15);
#pragma unroll
      for (int r = 0; r < 4; ++r) {
        const float bv = __half2float(bb[(size_t)(irow_base + r) * NN + jcol]);
        s[jt][r] = fmaf(s[jt][r], 0.125f, bv) + smask[jcol];
      }
    }
    // online softmax per row (rows live across lanes 0-15 of each 16-group)
    float alpha[4];
#pragma unroll
    for (int r = 0; r < 4; ++r) {
      float tm = fmaxf(fmaxf(s[0][r], s[1][r]), fmaxf(s[2][r], s[3][r]));
      tm = fmaxf(tm, __shfl_xor(tm, 1));
      tm = fmaxf(tm, __shfl_xor(tm, 2));
      tm = fmaxf(tm, __shfl_xor(tm, 4));
      tm = fmaxf(tm, __shfl_xor(tm, 8));
      const float mn = fmaxf(mrow[r], tm);
      alpha[r] = __expf(mrow[r] - mn);
      mrow[r] = mn;
      float ts = 0.f;
#pragma unroll
      for (int jt = 0; jt < 4; ++jt) {
        const float p = __expf(s[jt][r] - mn);
        s[jt][r] = p;
        ts += p;
      }
      ts += __shfl_xor(ts, 1);
      ts += __shfl_xor(ts, 2);
      ts += __shfl_xor(ts, 4);
      ts += __shfl_xor(ts, 8);
      lrow[r] = lrow[r] * alpha[r] + ts;
    }
#pragma unroll
    for (int d = 0; d < 4; ++d)
#pragma unroll
      for (int r = 0; r < 4; ++r) acc[d][r] *= alpha[r];
    // P -> bf16 -> per-wave LDS (swizzled scalar writes)
#pragma unroll
    for (int jt = 0; jt < 4; ++jt)
#pragma unroll
      for (int r = 0; r < 4; ++r)
        *(unsigned short*)&ps[w][swz128(((lane >> 4) << 2) + r, jt * 32 + 2 * (lane & 15))] =
            f2bf(s[jt][r]);
    __syncthreads();  // V^T staged + own P visible
    // PV accumulate
    short8v pf[2];
#pragma unroll
    for (int kc = 0; kc < 2; ++kc)
      pf[kc] = *(const short8v*)&ps[w][swz128(lane & 15, kc * 64 + (lane >> 4) * 16)];
#pragma unroll
    for (int d = 0; d < 4; ++d) {
      short8v vf0 = *(const short8v*)&vt[swz128(d * 16 + (lane & 15), (lane >> 4) * 16)];
      short8v vf1 = *(const short8v*)&vt[swz128(d * 16 + (lane & 15), 64 + (lane >> 4) * 16)];
      acc[d] = __builtin_amdgcn_mfma_f32_16x16x32_bf16(pf[0], vf0, acc[d], 0, 0, 0);
      acc[d] = __builtin_amdgcn_mfma_f32_16x16x32_bf16(pf[1], vf1, acc[d], 0, 0, 0);
    }
    __syncthreads();  // before next V^T overwrite
  }
  // epilogue: normalize, store attn_out bf16 [b][n][h*64+dh]
#pragma unroll
  for (int d = 0; d < 4; ++d) {
#pragma unroll
    for (int r = 0; r < 4; ++r) {
      const int row = irow_base + r;
      ao[(size_t)(b_ * NN + row) * 512 + h_ * DHH + d * 16 + (lane & 15)] =
          f2bf(acc[d][r] / lrow[r]);
    }
  }
}

extern "C" void kernel_launch(void* const* d_in, const int* in_sizes, int n_in,
                              void* d_out, int out_size, void* d_ws, size_t ws_size,
                              hipStream_t stream) {
  const float* h     = (const float*)d_in[0];
  const float* v     = (const float*)d_in[1];
  const int*   m     = (const int*)d_in[2];
  const int*   tti   = (const int*)d_in[3];
  const float* W_qkv = (const float*)d_in[4];
  const float* W_out = (const float*)d_in[5];
  const float* W1    = (const float*)d_in[6];
  const float* b1    = (const float*)d_in[7];
  const float* W2    = (const float*)d_in[8];
  const float* b2    = (const float*)d_in[9];
  float* out = (float*)d_out;
  unsigned char* ws = (unsigned char*)d_ws;

  unsigned short* h_bf  = (unsigned short*)(ws + 0);
  unsigned short* q_bf  = (unsigned short*)(ws + 8388608);
  unsigned short* k_bf  = (unsigned short*)(ws + 16777216);
  unsigned short* v_bf  = (unsigned short*)(ws + 25165824);
  unsigned short* ao_bf = (unsigned short*)(ws + 33554432);
  unsigned short* WqT   = (unsigned short*)(ws + 41943040);
  unsigned short* WoT   = (unsigned short*)(ws + 43515904);
  __half* bias          = (__half*)(ws + 44040192);

  cvt_bf<<<4096, 256, 0, stream>>>(h, h_bf, 16 * NN * 512);
  transpose_cvt<<<dim3(16, 48), 256, 0, stream>>>(W_qkv, WqT, 512, 1536);
  transpose_cvt<<<dim3(16, 16), 256, 0, stream>>>(W_out, WoT, 512, 512);
  gemm_qkv<<<dim3(64, 12), 256, 0, stream>>>(h_bf, WqT, q_bf, k_bf, v_bf);
  bias_mlp<<<dim3(512, 16), 256, 0, stream>>>(v, tti, W1, b1, W2, b2, bias);
  attn_mfma<<<dim3(8, 8, 16), 256, 0, stream>>>(q_bf, k_bf, v_bf, bias, m, ao_bf);
  gemm_out<<<dim3(64, 4), 256, 0, stream>>>(ao_bf, WoT, m, out);
}

// Round 3
// 151.260 us; speedup vs baseline: 3.8511x; 1.4087x over previous
//
#include <hip/hip_runtime.h>
#include <hip/hip_bf16.h>
#include <hip/hip_fp16.h>

// B=16, N=512, D=512, H=8, DH=64, PD=9, HID=32
#define NN 512
#define HH 8
#define DHH 64

typedef __attribute__((ext_vector_type(8))) short short8v;
typedef __attribute__((ext_vector_type(8))) unsigned short ushort8v;
typedef __attribute__((ext_vector_type(4))) unsigned short ushort4v;
typedef __attribute__((ext_vector_type(4))) float f32x4;
typedef __attribute__((ext_vector_type(8))) _Float16 f16x8;
typedef __attribute__((ext_vector_type(4))) _Float16 f16x4;

__device__ __forceinline__ unsigned short f2bf(float x) {
  unsigned u = __builtin_bit_cast(unsigned, x);
  u += 0x7FFFu + ((u >> 16) & 1u);
  return (unsigned short)(u >> 16);
}
// swizzles: XOR a row-dependent 16B slot into the byte-column (T2, rule #21 both-sides)
__device__ __forceinline__ int swz64(int r, int cb) { return r * 64 + (cb ^ (((r >> 1) & 3) << 4)); }
__device__ __forceinline__ int swz128(int r, int cb) { return r * 128 + (cb ^ ((r & 7) << 4)); }

// ---------------- fp32 -> bf16 elementwise ----------------
__global__ __launch_bounds__(256) void cvt_bf(const float* __restrict__ src,
                                              unsigned short* __restrict__ dst, int n) {
  int i = (blockIdx.x * 256 + threadIdx.x) * 4;
  if (i < n) {
    float4 v = *(const float4*)&src[i];
    ushort4v o;
    o[0] = f2bf(v.x); o[1] = f2bf(v.y); o[2] = f2bf(v.z); o[3] = f2bf(v.w);
    *(ushort4v*)&dst[i] = o;
  }
}

// ---------------- transpose + cvt: src fp32 [R][C] -> dst bf16 [C][R] ----------------
__global__ __launch_bounds__(256) void transpose_cvt(const float* __restrict__ src,
                                                     unsigned short* __restrict__ dst,
                                                     int R, int C) {
  __shared__ float t[32][33];
  const int r0 = blockIdx.x * 32, c0 = blockIdx.y * 32;
  const int rr = threadIdx.x >> 3, c4 = (threadIdx.x & 7) * 4;
  float4 v = *(const float4*)&src[(size_t)(r0 + rr) * C + c0 + c4];
  t[rr][c4 + 0] = v.x; t[rr][c4 + 1] = v.y; t[rr][c4 + 2] = v.z; t[rr][c4 + 3] = v.w;
  __syncthreads();
  ushort4v o;
#pragma unroll
  for (int e = 0; e < 4; ++e) o[e] = f2bf(t[c4 + e][rr]);
  *(ushort4v*)&dst[(size_t)(c0 + rr) * R + r0 + c4] = o;
}

// ---------------- shared 128x128 bf16 MFMA GEMM body (BK=32, 4 waves) ----------------
__device__ __forceinline__ void gemm128_body(const unsigned short* __restrict__ A,
                                             const unsigned short* __restrict__ Bt,
                                             int ldk, int m0, int n0,
                                             f32x4 acc[4][4], unsigned char* smem) {
  const int tid = threadIdx.x, lane = tid & 63, wid = tid >> 6;
  const int wm = wid >> 1, wn = wid & 1;
  int aoff[4], boff[4];
#pragma unroll
  for (int i = 0; i < 4; ++i) {
    aoff[i] = swz64(wm * 64 + i * 16 + (lane & 15), (lane >> 4) * 16);
    boff[i] = 8192 + swz64(wn * 64 + i * 16 + (lane & 15), (lane >> 4) * 16);
  }
  for (int k0 = 0; k0 < ldk; k0 += 32) {
#pragma unroll
    for (int p = 0; p < 2; ++p) {
      const int idx = p * 256 + tid;
      const int r = idx >> 2, cg = idx & 3;
      ushort8v av = *(const ushort8v*)&A[(size_t)(m0 + r) * ldk + k0 + cg * 8];
      *(ushort8v*)&smem[swz64(r, cg * 16)] = av;
      ushort8v bv = *(const ushort8v*)&Bt[(size_t)(n0 + r) * ldk + k0 + cg * 8];
      *(ushort8v*)&smem[8192 + swz64(r, cg * 16)] = bv;
    }
    __syncthreads();
    short8v a[4], b[4];
#pragma unroll
    for (int i = 0; i < 4; ++i) {
      a[i] = *(const short8v*)&smem[aoff[i]];
      b[i] = *(const short8v*)&smem[boff[i]];
    }
#pragma unroll
    for (int i = 0; i < 4; ++i)
#pragma unroll
      for (int j = 0; j < 4; ++j)
        acc[i][j] = __builtin_amdgcn_mfma_f32_16x16x32_bf16(a[i], b[j], acc[i][j], 0, 0, 0);
    __syncthreads();
  }
}

// ---------------- QKV GEMM: h_bf[8192][512] @ WqT[1536][512]^T -> q/k/v bf16 ----------------
__global__ __launch_bounds__(256) void gemm_qkv(const unsigned short* __restrict__ A,
                                                const unsigned short* __restrict__ Bt,
                                                unsigned short* __restrict__ q,
                                                unsigned short* __restrict__ k,
                                                unsigned short* __restrict__ v) {
  __shared__ unsigned char smem[16384];
  f32x4 acc[4][4];
  const f32x4 z = {0.f, 0.f, 0.f, 0.f};
#pragma unroll
  for (int i = 0; i < 4; ++i)
#pragma unroll
    for (int j = 0; j < 4; ++j) acc[i][j] = z;
  gemm128_body(A, Bt, 512, blockIdx.x * 128, blockIdx.y * 128, acc, smem);
  const int lane = threadIdx.x & 63, wid = threadIdx.x >> 6;
  const int wm = wid >> 1, wn = wid & 1;
#pragma unroll
  for (int i = 0; i < 4; ++i) {
    const int row0 = blockIdx.x * 128 + wm * 64 + i * 16 + ((lane >> 4) << 2);
#pragma unroll
    for (int j = 0; j < 4; ++j) {
      const int col = blockIdx.y * 128 + wn * 64 + j * 16 + (lane & 15);
      const int part = col >> 9, head = (col >> 6) & 7, dh = col & 63;
      unsigned short* dst = (part == 0) ? q : ((part == 1) ? k : v);
#pragma unroll
      for (int rr = 0; rr < 4; ++rr) {
        const int row = row0 + rr;
        const int b_ = row >> 9, n_ = row & 511;
        dst[(((b_ * HH + head) * NN) + n_) * DHH + dh] = f2bf(acc[i][j][rr]);
      }
    }
  }
}

// ---------------- out GEMM: ao_bf[8192][512] @ WoT[512][512]^T -> fp32 out (masked) ----------------
__global__ __launch_bounds__(256) void gemm_out(const unsigned short* __restrict__ A,
                                                const unsigned short* __restrict__ Bt,
                                                const int* __restrict__ msk,
                                                float* __restrict__ out) {
  __shared__ unsigned char smem[16384];
  f32x4 acc[4][4];
  const f32x4 z = {0.f, 0.f, 0.f, 0.f};
#pragma unroll
  for (int i = 0; i < 4; ++i)
#pragma unroll
    for (int j = 0; j < 4; ++j) acc[i][j] = z;
  gemm128_body(A, Bt, 512, blockIdx.x * 128, blockIdx.y * 128, acc, smem);
  const int lane = threadIdx.x & 63, wid = threadIdx.x >> 6;
  const int wm = wid >> 1, wn = wid & 1;
#pragma unroll
  for (int i = 0; i < 4; ++i) {
    const int row0 = blockIdx.x * 128 + wm * 64 + i * 16 + ((lane >> 4) << 2);
#pragma unroll
    for (int j = 0; j < 4; ++j) {
      const int col = blockIdx.y * 128 + wn * 64 + j * 16 + (lane & 15);
#pragma unroll
      for (int rr = 0; rr < 4; ++rr) {
        const int row = row0 + rr;
        const float mm = (msk[row] != 0) ? 1.f : 0.f;
        out[(size_t)row * 512 + col] = acc[i][j][rr] * mm;
      }
    }
  }
}

// ---------------- pairwise bias MLP via f16 MFMA -> fp16 bias[b][h][i][j] ----------------
// block = (i, b), 256 threads = 4 waves; wave w covers j = w*16 + 64*it, 16 j per iter.
// Per iter: A = features [16 pairs][K=9 pad 32] f16 (in-reg), hidden = relu(A@W1+b1) via
// 2 MFMA, LDS transpose, out = hidden@W2+b2 via 1 MFMA, store 8 heads fp16.
__global__ __launch_bounds__(256) void bias_mlp_mfma(
    const float* __restrict__ v, const int* __restrict__ tti,
    const float* __restrict__ W1, const float* __restrict__ b1,
    const float* __restrict__ W2, const float* __restrict__ b2,
    __half* __restrict__ bias) {
  __shared__ float sv[NN][4];
  __shared__ int stt[NN];
  __shared__ _Float16 hbuf[4][16 * 40];  // per-wave [16 rows][80B rows]
  const int tid = threadIdx.x, lane = tid & 63, w = tid >> 6;
  const int i = blockIdx.x, b = blockIdx.y;
  const int l16 = lane & 15, lg = lane >> 4;
  for (int idx = tid; idx < NN; idx += 256) {
    *(float4*)&sv[idx][0] = *(const float4*)&v[(b * NN + idx) * 4];
    stt[idx] = tti[idx];
  }
  // resident B-fragments: W1 (K=9 pad 32, two 16-col tiles), W2 (8 cols pad 16)
  f16x8 w1f[2], w2f;
#pragma unroll
  for (int t = 0; t < 2; ++t)
#pragma unroll
    for (int e = 0; e < 8; ++e) {
      const int kk = lg * 8 + e;
      w1f[t][e] = (kk < 9) ? (_Float16)W1[kk * 32 + t * 16 + l16] : (_Float16)0.f;
    }
#pragma unroll
  for (int e = 0; e < 8; ++e)
    w2f[e] = (l16 < 8) ? (_Float16)W2[(lg * 8 + e) * 8 + l16] : (_Float16)0.f;
  const float b1v0 = b1[l16], b1v1 = b1[16 + l16];
  const float b2v = (l16 < 8) ? b2[l16] : 0.f;
  __syncthreads();
  const float4 vi = *(const float4*)&sv[i][0];
  const int ti = stt[i];
  _Float16* hb = &hbuf[w][0];
  for (int j0 = w * 16; j0 < NN; j0 += 64) {
    const int j = j0 + l16;
    const float4 vj = *(const float4*)&sv[j][0];
    f16x8 af = {0, 0, 0, 0, 0, 0, 0, 0};
    if (lg == 0) {
      af[0] = (_Float16)(vi.x - vj.x); af[1] = (_Float16)(vi.y - vj.y);
      af[2] = (_Float16)(vi.z - vj.z); af[3] = (_Float16)(vi.w - vj.w);
      af[4] = (_Float16)(vi.x * vj.x); af[5] = (_Float16)(vi.y * vj.y);
      af[6] = (_Float16)(vi.z * vj.z); af[7] = (_Float16)(vi.w * vj.w);
    } else if (lg == 1) {
      af[0] = (ti == stt[j]) ? (_Float16)1.f : (_Float16)0.f;
    }
    f32x4 h0 = {b1v0, b1v0, b1v0, b1v0};
    f32x4 h1 = {b1v1, b1v1, b1v1, b1v1};
    h0 = __builtin_amdgcn_mfma_f32_16x16x32_f16(af, w1f[0], h0, 0, 0, 0);
    h1 = __builtin_amdgcn_mfma_f32_16x16x32_f16(af, w1f[1], h1, 0, 0, 0);
    // relu + transpose through per-wave LDS (row stride 40 halfs = 80B -> 2-way free reads)
#pragma unroll
    for (int r = 0; r < 4; ++r) {
      const int row = lg * 4 + r;
      hb[row * 40 + l16] = (_Float16)fmaxf(h0[r], 0.f);
      hb[row * 40 + 16 + l16] = (_Float16)fmaxf(h1[r], 0.f);
    }
    f16x8 af2 = *(const f16x8*)&hb[l16 * 40 + lg * 8];
    f32x4 o = {b2v, b2v, b2v, b2v};
    o = __builtin_amdgcn_mfma_f32_16x16x32_f16(af2, w2f, o, 0, 0, 0);
    if (l16 < 8) {
      f16x4 pk;
#pragma unroll
      for (int r = 0; r < 4; ++r) pk[r] = (_Float16)o[r];
      *(f16x4*)&bias[((size_t)(b * HH + l16) * NN + i) * NN + j0 + lg * 4] = pk;
    }
  }
}

// ---------------- MFMA flash attention ----------------
// block = (it: 64 q-rows, h, b); 4 waves, wave w owns rows it*64 + w*16 .. +15
__global__ __launch_bounds__(256) void attn_mfma(
    const unsigned short* __restrict__ q, const unsigned short* __restrict__ k,
    const unsigned short* __restrict__ v, const __half* __restrict__ bias,
    const int* __restrict__ msk, unsigned short* __restrict__ ao) {
  __shared__ unsigned char vt[8192];     // V^T tile, [64 dh][128B row] swizzled
  __shared__ unsigned char ps[4][2048];  // per-wave P tile [16][128B] swizzled
  __shared__ float smask[NN];
  const int tid = threadIdx.x, lane = tid & 63, w = tid >> 6;
  const int it = blockIdx.x, h_ = blockIdx.y, b_ = blockIdx.z;
  const int bh = b_ * HH + h_;
  const unsigned short* qb = q + ((size_t)bh * NN + it * 64) * DHH;
  const unsigned short* kb = k + (size_t)bh * NN * DHH;
  const unsigned short* vb = v + (size_t)bh * NN * DHH;
  const __half* bb = bias + (size_t)bh * NN * NN;
  for (int j = tid; j < NN; j += 256) smask[j] = (msk[b_ * NN + j] != 0) ? 0.f : -1e30f;
  short8v qf[2];
#pragma unroll
  for (int kc = 0; kc < 2; ++kc)
    qf[kc] = *(const short8v*)&qb[(w * 16 + (lane & 15)) * DHH + kc * 32 + (lane >> 4) * 8];
  f32x4 acc[4];
  const f32x4 z = {0.f, 0.f, 0.f, 0.f};
#pragma unroll
  for (int d = 0; d < 4; ++d) acc[d] = z;
  float mrow[4], lrow[4];
#pragma unroll
  for (int r = 0; r < 4; ++r) { mrow[r] = -1e30f; lrow[r] = 0.f; }
  __syncthreads();
  const int irow_base = it * 64 + w * 16 + ((lane >> 4) << 2);
  for (int j0 = 0; j0 < NN; j0 += 64) {
#pragma unroll
    for (int p = 0; p < 2; ++p) {
      const int idx = p * 256 + tid;
      const int j = idx & 63, dh0 = (idx >> 6) * 8;
      ushort8v v8 = *(const ushort8v*)&vb[(j0 + j) * DHH + dh0];
#pragma unroll
      for (int e = 0; e < 8; ++e)
        *(unsigned short*)&vt[swz128(dh0 + e, 2 * j)] = v8[e];
    }
    f32x4 s[4];
#pragma unroll
    for (int jt = 0; jt < 4; ++jt) {
      const unsigned short* kr = &kb[(j0 + jt * 16 + (lane & 15)) * DHH + (lane >> 4) * 8];
      short8v kf0 = *(const short8v*)&kr[0];
      short8v kf1 = *(const short8v*)&kr[32];
      f32x4 t = z;
      t = __builtin_amdgcn_mfma_f32_16x16x32_bf16(qf[0], kf0, t, 0, 0, 0);
      t = __builtin_amdgcn_mfma_f32_16x16x32_bf16(qf[1], kf1, t, 0, 0, 0);
      s[jt] = t;
    }
#pragma unroll
    for (int jt = 0; jt < 4; ++jt) {
      const int jcol = j0 + jt * 16 + (lane & 15);
#pragma unroll
      for (int r = 0; r < 4; ++r) {
        const float bv = __half2float(bb[(size_t)(irow_base + r) * NN + jcol]);
        s[jt][r] = fmaf(s[jt][r], 0.125f, bv) + smask[jcol];
      }
    }
    float alpha[4];
#pragma unroll
    for (int r = 0; r < 4; ++r) {
      float tm = fmaxf(fmaxf(s[0][r], s[1][r]), fmaxf(s[2][r], s[3][r]));
      tm = fmaxf(tm, __shfl_xor(tm, 1));
      tm = fmaxf(tm, __shfl_xor(tm, 2));
      tm = fmaxf(tm, __shfl_xor(tm, 4));
      tm = fmaxf(tm, __shfl_xor(tm, 8));
      const float mn = fmaxf(mrow[r], tm);
      alpha[r] = __expf(mrow[r] - mn);
      mrow[r] = mn;
      float ts = 0.f;
#pragma unroll
      for (int jt = 0; jt < 4; ++jt) {
        const float p = __expf(s[jt][r] - mn);
        s[jt][r] = p;
        ts += p;
      }
      ts += __shfl_xor(ts, 1);
      ts += __shfl_xor(ts, 2);
      ts += __shfl_xor(ts, 4);
      ts += __shfl_xor(ts, 8);
      lrow[r] = lrow[r] * alpha[r] + ts;
    }
#pragma unroll
    for (int d = 0; d < 4; ++d)
#pragma unroll
      for (int r = 0; r < 4; ++r) acc[d][r] *= alpha[r];
#pragma unroll
    for (int jt = 0; jt < 4; ++jt)
#pragma unroll
      for (int r = 0; r < 4; ++r)
        *(unsigned short*)&ps[w][swz128(((lane >> 4) << 2) + r, jt * 32 + 2 * (lane & 15))] =
            f2bf(s[jt][r]);
    __syncthreads();
    short8v pf[2];
#pragma unroll
    for (int kc = 0; kc < 2; ++kc)
      pf[kc] = *(const short8v*)&ps[w][swz128(lane & 15, kc * 64 + (lane >> 4) * 16)];
#pragma unroll
    for (int d = 0; d < 4; ++d) {
      short8v vf0 = *(const short8v*)&vt[swz128(d * 16 + (lane & 15), (lane >> 4) * 16)];
      short8v vf1 = *(const short8v*)&vt[swz128(d * 16 + (lane & 15), 64 + (lane >> 4) * 16)];
      acc[d] = __builtin_amdgcn_mfma_f32_16x16x32_bf16(pf[0], vf0, acc[d], 0, 0, 0);
      acc[d] = __builtin_amdgcn_mfma_f32_16x16x32_bf16(pf[1], vf1, acc[d], 0, 0, 0);
    }
    __syncthreads();
  }
#pragma unroll
  for (int d = 0; d < 4; ++d) {
#pragma unroll
    for (int r = 0; r < 4; ++r) {
      const int row = irow_base + r;
      ao[(size_t)(b_ * NN + row) * 512 + h_ * DHH + d * 16 + (lane & 15)] =
          f2bf(acc[d][r] / lrow[r]);
    }
  }
}

extern "C" void kernel_launch(void* const* d_in, const int* in_sizes, int n_in,
                              void* d_out, int out_size, void* d_ws, size_t ws_size,
                              hipStream_t stream) {
  const float* h     = (const float*)d_in[0];
  const float* v     = (const float*)d_in[1];
  const int*   m     = (const int*)d_in[2];
  const int*   tti   = (const int*)d_in[3];
  const float* W_qkv = (const float*)d_in[4];
  const float* W_out = (const float*)d_in[5];
  const float* W1    = (const float*)d_in[6];
  const float* b1    = (const float*)d_in[7];
  const float* W2    = (const float*)d_in[8];
  const float* b2    = (const float*)d_in[9];
  float* out = (float*)d_out;
  unsigned char* ws = (unsigned char*)d_ws;

  unsigned short* h_bf  = (unsigned short*)(ws + 0);
  unsigned short* q_bf  = (unsigned short*)(ws + 8388608);
  unsigned short* k_bf  = (unsigned short*)(ws + 16777216);
  unsigned short* v_bf  = (unsigned short*)(ws + 25165824);
  unsigned short* ao_bf = (unsigned short*)(ws + 33554432);
  unsigned short* WqT   = (unsigned short*)(ws + 41943040);
  unsigned short* WoT   = (unsigned short*)(ws + 43515904);
  __half* bias          = (__half*)(ws + 44040192);

  cvt_bf<<<4096, 256, 0, stream>>>(h, h_bf, 16 * NN * 512);
  transpose_cvt<<<dim3(16, 48), 256, 0, stream>>>(W_qkv, WqT, 512, 1536);
  transpose_cvt<<<dim3(16, 16), 256, 0, stream>>>(W_out, WoT, 512, 512);
  gemm_qkv<<<dim3(64, 12), 256, 0, stream>>>(h_bf, WqT, q_bf, k_bf, v_bf);
  bias_mlp_mfma<<<dim3(512, 16), 256, 0, stream>>>(v, tti, W1, b1, W2, b2, bias);
  attn_mfma<<<dim3(8, 8, 16), 256, 0, stream>>>(q_bf, k_bf, v_bf, bias, m, ao_bf);
  gemm_out<<<dim3(64, 4), 256, 0, stream>>>(ao_bf, WoT, m, out);
}